// Round 6
// baseline (396.371 us; speedup 1.0000x reference)
//
#include <hip/hip_runtime.h>

// MSE between pred_iou[32,8] and binary-Jaccard IoU from pred_masks
// [32,8,512,512] fp32 (>0.5) vs target_masks [32,512,512] int32 (>0).
//
// R6 == R5 with ONE change: no nontemporal loads (plain cached loads).
// Testing whether the nt (LLC no-allocate) policy was capping the pure-read
// path at ~2.5 TB/s across R3/R4/R5 — it was the single invariant among
// three otherwise-different access structures that all timed identically.
//
//  Phase 1: tgt (32 MB) -> wave ballots, 1 bit/elem. 1 MB total.
//  Phase 2: each block = ONE contiguous 128 KB linear stream of ONE pred
//           mask; counting is popcount(ballot(p>0.5) & w).
// HBM floor: 256 MB pred + 32 MB tgt + ~2 MB bitmask ~ 46 us at 6.3 TB/s.

#define BS      32
#define NMASKS  8
#define HW      (512 * 512)              // 262144 elems per mask
#define WPI     (HW / 256)               // 1024 windows per image
#define TOTAL_W (BS * WPI)               // 32768 windows
#define GROUPS  8                        // spans per (b,n) mask
#define SPAN    (HW / GROUPS)            // 32768 elems = 128 KB
#define BLOCK   256
#define NPAIRS  (BS * NMASKS)            // 256
#define ITERS   (SPAN / (BLOCK * 4))     // 32 float4-iters per thread

typedef int   iv4 __attribute__((ext_vector_type(4)));
typedef float fv4 __attribute__((ext_vector_type(4)));

// ---- phase 1: build ballot bitmask (32 MB -> 1 MB) ----
__global__ __launch_bounds__(BLOCK) void build_bitmask(
    const int* __restrict__ tgt,
    unsigned long long* __restrict__ bm)
{
    const int lane  = threadIdx.x & 63;
    const int gwave = blockIdx.x * (BLOCK / 64) + (threadIdx.x >> 6); // 0..1023
    const int w0    = gwave * (TOTAL_W / 1024);                       // 32 windows/wave

#pragma unroll 4
    for (int i = 0; i < TOTAL_W / 1024; ++i) {
        const int w = w0 + i;
        const iv4 t4 = *(const iv4*)(tgt + (size_t)w * 256 + (size_t)lane * 4);
        const unsigned long long b0 = __ballot(t4.x > 0);
        const unsigned long long b1 = __ballot(t4.y > 0);
        const unsigned long long b2 = __ballot(t4.z > 0);
        const unsigned long long b3 = __ballot(t4.w > 0);
        if (lane == 0) {
            unsigned long long* p = bm + (size_t)w * 4;
            p[0] = b0; p[1] = b1; p[2] = b2; p[3] = b3;
        }
    }
}

// ---- phase 2: linear pred streams + ballot counting ----
__global__ __launch_bounds__(BLOCK, 8) void iou_count_kernel(
    const float* __restrict__ pred,
    const unsigned long long* __restrict__ bm,
    unsigned long long* __restrict__ ws)
{
    // blockIdx = b*64 + n*8 + grp
    const int idx = blockIdx.x;
    const int b   = idx >> 6;
    const int n   = (idx >> 3) & 7;
    const int grp = idx & 7;
    const int tid = threadIdx.x;
    const int wv  = tid >> 6;

    const float* pbase =
        pred + ((size_t)(b * NMASKS + n)) * HW + (size_t)grp * SPAN + (size_t)tid * 4;

    // window index for this wave at it=0; advances by 4 per iter.
    const int wbase = __builtin_amdgcn_readfirstlane(
        b * WPI + grp * (SPAN / 256) + wv);

    unsigned int inter = 0u, uni = 0u;

#pragma unroll 4
    for (int it = 0; it < ITERS; ++it) {
        const fv4 p4 = *(const fv4*)(pbase + (size_t)it * (BLOCK * 4));

        const unsigned long long* wp = bm + (size_t)(wbase + it * 4) * 4;
        const unsigned long long w0 = wp[0], w1 = wp[1], w2 = wp[2], w3 = wp[3];

        const unsigned long long p0 = __ballot(p4.x > 0.5f);
        const unsigned long long p1 = __ballot(p4.y > 0.5f);
        const unsigned long long p2 = __ballot(p4.z > 0.5f);
        const unsigned long long p3 = __ballot(p4.w > 0.5f);

        inter += (unsigned)(__popcll(p0 & w0) + __popcll(p1 & w1) +
                            __popcll(p2 & w2) + __popcll(p3 & w3));
        uni   += (unsigned)(__popcll(p0 | w0) + __popcll(p1 | w1) +
                            __popcll(p2 | w2) + __popcll(p3 | w3));
    }

    // per-wave scalars -> LDS -> one u64 partial per block (counts <= 8192
    // per wave, <= 32768 per block: no cross-field carry in the pack).
    __shared__ unsigned long long s[BLOCK / 64];
    if ((tid & 63) == 0)
        s[wv] = ((unsigned long long)inter << 32) | (unsigned long long)uni;
    __syncthreads();

    if (tid == 0)
        ws[(size_t)grp * NPAIRS + (size_t)b * NMASKS + n] =
            s[0] + s[1] + s[2] + s[3];
}

__global__ __launch_bounds__(NPAIRS) void finalize_kernel(
    const float* __restrict__ pred_iou,
    const unsigned long long* __restrict__ ws,
    float* __restrict__ out)
{
    const int i = threadIdx.x;   // pair 0..255
    unsigned long long v = 0ull;
#pragma unroll
    for (int g = 0; g < GROUPS; ++g)
        v += ws[(size_t)g * NPAIRS + i];

    const unsigned int inter = (unsigned int)(v >> 32);
    const unsigned int uni   = (unsigned int)(v & 0xffffffffu);
    // reference: where(union>0, inter/max(union,1), 0); union>=1 when >0
    const float iou = (uni > 0u) ? ((float)inter / (float)uni) : 0.0f;
    const float d = pred_iou[i] - iou;
    out[i] = d * d;
}

extern "C" void kernel_launch(void* const* d_in, const int* in_sizes, int n_in,
                              void* d_out, int out_size, void* d_ws, size_t ws_size,
                              hipStream_t stream) {
    const float* pred_iou = (const float*)d_in[0];          // [32,8]
    const int*   tgt      = (const int*)d_in[1];            // [32,512,512]
    const float* pred     = (const float*)d_in[2];          // [32,8,512,512]
    float* out = (float*)d_out;

    // ws layout: [0,16KB) block partials; [64KB,64KB+1MB) bitmask.
    unsigned long long* partials = (unsigned long long*)d_ws;
    unsigned long long* bm = (unsigned long long*)((char*)d_ws + (64 << 10));

    build_bitmask<<<1024 / (BLOCK / 64), BLOCK, 0, stream>>>(tgt, bm);
    iou_count_kernel<<<BS * NMASKS * GROUPS, BLOCK, 0, stream>>>(pred, bm, partials);
    finalize_kernel<<<1, NPAIRS, 0, stream>>>(pred_iou, partials, out);
}

// Round 7
// 391.169 us; speedup vs baseline: 1.0133x; 1.0133x over previous
//
#include <hip/hip_runtime.h>

// MSE between pred_iou[32,8] and binary-Jaccard IoU from pred_masks
// [32,8,512,512] fp32 (>0.5) vs target_masks [32,512,512] int32 (>0).
//
// R7: decouple vmcnt from bitmask consumption + deep software pipeline.
//  Phase 1: tgt (32 MB) -> wave ballots, 1 bit/elem, 1 MB table (unchanged).
//  Phase 2: per block, stage the block's 4 KB bitmask slice into LDS ONCE
//           (bm reads become lgkmcnt ds_read broadcasts), then stream the
//           128 KB pred span in double-buffered groups of 8 dwordx4 loads:
//           compiler emits s_waitcnt vmcnt(8)-style fine-grained waits, so
//           each wave keeps ~8 HBM loads in flight continuously instead of
//           draining the FIFO every 4 loads to reach the bm words.
// HBM floor: 256 MB pred + 32 MB tgt + ~2 MB bitmask ~ 46 us at 6.3 TB/s.

#define BS      32
#define NMASKS  8
#define HW      (512 * 512)              // 262144 elems per mask
#define WPI     (HW / 256)               // 1024 windows per image
#define TOTAL_W (BS * WPI)               // 32768 windows
#define GROUPS  8                        // spans per (b,n) mask
#define SPAN    (HW / GROUPS)            // 32768 elems = 128 KB
#define WPB     (SPAN / 256)             // 128 windows per block
#define BLOCK   256
#define NPAIRS  (BS * NMASKS)            // 256
#define ITERS   (SPAN / (BLOCK * 4))     // 32 float4-iters per thread
#define PG      8                        // pipeline group size
#define NGRP    (ITERS / PG)             // 4 groups

typedef int    iv4 __attribute__((ext_vector_type(4)));
typedef float  fv4 __attribute__((ext_vector_type(4)));
typedef unsigned long long u64;
typedef u64    uv2 __attribute__((ext_vector_type(2)));

// ---- phase 1: build ballot bitmask (32 MB -> 1 MB) ----
__global__ __launch_bounds__(BLOCK) void build_bitmask(
    const int* __restrict__ tgt,
    u64* __restrict__ bm)
{
    const int lane  = threadIdx.x & 63;
    const int gwave = blockIdx.x * (BLOCK / 64) + (threadIdx.x >> 6); // 0..1023
    const int w0    = gwave * (TOTAL_W / 1024);                       // 32 windows/wave

#pragma unroll 4
    for (int i = 0; i < TOTAL_W / 1024; ++i) {
        const int w = w0 + i;
        const iv4 t4 = __builtin_nontemporal_load(
            (const iv4*)(tgt + (size_t)w * 256 + (size_t)lane * 4));
        const u64 b0 = __ballot(t4.x > 0);
        const u64 b1 = __ballot(t4.y > 0);
        const u64 b2 = __ballot(t4.z > 0);
        const u64 b3 = __ballot(t4.w > 0);
        if (lane == 0) {
            u64* p = bm + (size_t)w * 4;
            p[0] = b0; p[1] = b1; p[2] = b2; p[3] = b3;
        }
    }
}

// ---- phase 2: pipelined linear pred streams, bm from LDS ----
__global__ __launch_bounds__(BLOCK, 4) void iou_count_kernel(
    const float* __restrict__ pred,
    const u64* __restrict__ bm,
    u64* __restrict__ ws)
{
    // blockIdx = b*64 + n*8 + grp
    const int idx = blockIdx.x;
    const int b   = idx >> 6;
    const int n   = (idx >> 3) & 7;
    const int grp = idx & 7;
    const int tid = threadIdx.x;
    const int wv  = tid >> 6;

    // stage this block's 128-window bitmask slice (4 KB) into LDS
    __shared__ u64 sbm[WPB * 4];                    // 512 u64
    {
        const size_t slice = ((size_t)b * WPI + (size_t)grp * WPB) * 4;
        *(uv2*)(sbm + 2 * tid) = *(const uv2*)(bm + slice + 2 * tid);
    }
    __syncthreads();

    const float* pbase =
        pred + ((size_t)(b * NMASKS + n)) * HW + (size_t)grp * SPAN + (size_t)tid * 4;

    unsigned int inter = 0u, uni = 0u;

    fv4 buf[2][PG];

    // prologue: issue group 0
#pragma unroll
    for (int j = 0; j < PG; ++j)
        buf[0][j] = __builtin_nontemporal_load(
            (const fv4*)(pbase + (size_t)j * (BLOCK * 4)));

    for (int g = 0; g < NGRP; ++g) {
        const int cur = g & 1;
        const int nxt = cur ^ 1;

        // issue next group before consuming current (stays in flight across
        // the consume loop -> fine-grained vmcnt waits, never drained to 0)
        if (g + 1 < NGRP) {
#pragma unroll
            for (int j = 0; j < PG; ++j)
                buf[nxt][j] = __builtin_nontemporal_load(
                    (const fv4*)(pbase + (size_t)((g + 1) * PG + j) * (BLOCK * 4)));
        }

#pragma unroll
        for (int j = 0; j < PG; ++j) {
            const int it = g * PG + j;
            const int wl = it * 4 + wv;             // window-local index
            const u64 w0 = sbm[wl * 4 + 0];         // LDS broadcast (lgkmcnt)
            const u64 w1 = sbm[wl * 4 + 1];
            const u64 w2 = sbm[wl * 4 + 2];
            const u64 w3 = sbm[wl * 4 + 3];

            const fv4 p4 = buf[cur][j];
            const u64 p0 = __ballot(p4.x > 0.5f);
            const u64 p1 = __ballot(p4.y > 0.5f);
            const u64 p2 = __ballot(p4.z > 0.5f);
            const u64 p3 = __ballot(p4.w > 0.5f);

            inter += (unsigned)(__popcll(p0 & w0) + __popcll(p1 & w1) +
                                __popcll(p2 & w2) + __popcll(p3 & w3));
            uni   += (unsigned)(__popcll(p0 | w0) + __popcll(p1 | w1) +
                                __popcll(p2 | w2) + __popcll(p3 | w3));
        }
    }

    // per-wave scalars -> LDS -> one u64 partial per block (counts <= 8192
    // per wave: no cross-field carry in the pack).
    __shared__ u64 s[BLOCK / 64];
    if ((tid & 63) == 0)
        s[wv] = ((u64)inter << 32) | (u64)uni;
    __syncthreads();

    if (tid == 0)
        ws[(size_t)grp * NPAIRS + (size_t)b * NMASKS + n] =
            s[0] + s[1] + s[2] + s[3];
}

__global__ __launch_bounds__(NPAIRS) void finalize_kernel(
    const float* __restrict__ pred_iou,
    const u64* __restrict__ ws,
    float* __restrict__ out)
{
    const int i = threadIdx.x;   // pair 0..255
    u64 v = 0ull;
#pragma unroll
    for (int g = 0; g < GROUPS; ++g)
        v += ws[(size_t)g * NPAIRS + i];

    const unsigned int inter = (unsigned int)(v >> 32);
    const unsigned int uni   = (unsigned int)(v & 0xffffffffu);
    // reference: where(union>0, inter/max(union,1), 0); union>=1 when >0
    const float iou = (uni > 0u) ? ((float)inter / (float)uni) : 0.0f;
    const float d = pred_iou[i] - iou;
    out[i] = d * d;
}

extern "C" void kernel_launch(void* const* d_in, const int* in_sizes, int n_in,
                              void* d_out, int out_size, void* d_ws, size_t ws_size,
                              hipStream_t stream) {
    const float* pred_iou = (const float*)d_in[0];          // [32,8]
    const int*   tgt      = (const int*)d_in[1];            // [32,512,512]
    const float* pred     = (const float*)d_in[2];          // [32,8,512,512]
    float* out = (float*)d_out;

    // ws layout: [0,16KB) block partials; [64KB,64KB+1MB) bitmask.
    u64* partials = (u64*)d_ws;
    u64* bm = (u64*)((char*)d_ws + (64 << 10));

    build_bitmask<<<1024 / (BLOCK / 64), BLOCK, 0, stream>>>(tgt, bm);
    iou_count_kernel<<<BS * NMASKS * GROUPS, BLOCK, 0, stream>>>(pred, bm, partials);
    finalize_kernel<<<1, NPAIRS, 0, stream>>>(pred_iou, partials, out);
}